// Round 14
// baseline (251.611 us; speedup 1.0000x reference)
//
#include <hip/hip_runtime.h>
#include <hip/hip_bf16.h>

#define DI __device__ __forceinline__

typedef __attribute__((ext_vector_type(8))) short bf16x8;
typedef __attribute__((ext_vector_type(4))) float f32x4;
typedef __attribute__((ext_vector_type(4))) _Float16 f16x4;

constexpr int XPAD = 264;   // k2 A-tile row stride
constexpr float LOG2E = 1.4426950408889634f;

DI float fexp(float x) { return __builtin_amdgcn_exp2f(x * LOG2E); }  // raw v_exp_f32
DI float frcp(float x) { return __builtin_amdgcn_rcpf(x); }           // raw v_rcp_f32

DI short f2bf(float f) {                 // fp32 -> bf16 via HW cvt
  __hip_bfloat16 h = __float2bfloat16(f);
  union { __hip_bfloat16 h; short s; } c; c.h = h; return c.s;
}

DI unsigned pk2(float a, float b) {      // two f32 -> packed bf16x2 (HW cvt_pk)
  union { __hip_bfloat162 h; unsigned u; } c;
  c.h.x = __float2bfloat16(a); c.h.y = __float2bfloat16(b);
  return c.u;
}

DI short f2h(float f) {                  // fp32 -> f16 bits
  _Float16 h = (_Float16)f;
  union { _Float16 h; short s; } c; c.h = h; return c.s;
}

DI f16x4 pkh4(float a, float b, float c, float d) {   // 4 f32 -> f16x4 (cvt_pkrtz)
  auto lo = __builtin_amdgcn_cvt_pkrtz(a, b);         // __fp16 ext_vector(2)
  auto hi = __builtin_amdgcn_cvt_pkrtz(c, d);
  union { struct { decltype(lo) l, h; } p; f16x4 v; } u;
  u.p.l = lo; u.p.h = hi;
  return u.v;
}

DI f16x4 ld4h(const short* p) {          // 4 f16 (8 B)
  union { uint2 u; f16x4 v; } c;
  c.u = *(const uint2*)p;
  return c.v;
}

DI f32x4 mfma16(bf16x8 a, bf16x8 b, f32x4 c) {
  // A: row=l&15, k=(l>>4)*8+j ; B: col=l&15, k=(l>>4)*8+j ; D: col=l&15, row=(l>>4)*4+reg
  return __builtin_amdgcn_mfma_f32_16x16x32_bf16(a, b, c, 0, 0, 0);
}

DI f32x4 mfmah(f16x4 a, f16x4 b, f32x4 c) {
  // 16x16x16 f16: A row=l&15, k=(l>>4)*4+j ; B col=l&15, k=(l>>4)*4+j ; D as above.
  // A/B fragment layout == D layout of the 16x16 family -> GEMM accumulators
  // convert to next-MFMA operands with an own-lane pack (no shfl, no LDS).
  return __builtin_amdgcn_mfma_f32_16x16x16f16(a, b, c, 0, 0, 0);
}

DI f32x4 fzero() { return f32x4{0.f, 0.f, 0.f, 0.f}; }

// Xs swizzled element index: row-major [64][256] bf16, XOR bits 3..5 of the
// element offset with row&7 -> b128 reads across rows hit all 32 banks.
DI int xsw(int row, int e) { return row * 256 + (e ^ ((row & 7) << 3)); }

// ---------------- K0: weights fp32 -> bf16 into ws (Wq pre-scaled) ----------------
__global__ void wconv_kernel(const float* __restrict__ a, const float* __restrict__ b,
                             const float* __restrict__ c, const float* __restrict__ d,
                             short* __restrict__ o) {
  int i = blockIdx.x * 256 + threadIdx.x;
  int mat = i >> 14;                         // block-uniform
  int off = (i & 16383) * 4;
  const float* s = (mat == 0) ? a : (mat == 1) ? b : (mat == 2) ? c : d;
  const float sc = (mat == 0) ? 0.125f : 1.0f;   // fold Ch^-0.5 into Wq
  float4 v = *(const float4*)(s + off);
  uint2 r; r.x = pk2(v.x * sc, v.y * sc); r.y = pk2(v.z * sc, v.w * sc);
  *(uint2*)(o + mat * 65536 + off) = r;
}

// ---------------- K1: fused QKV + softmaxes + linear attention (r11, best) -------
// One WG = 4 consecutive pixels, 256 threads (4 waves). Each wave = one head.
// Direct-x staging (4x4 float4 register transpose -> swizzled Xs), Q-first ->
// qsg (L2-hot), fexp/frcp, register-kv stage B, per-pass accumulators die into
// 16-reg f16 frags, (256,4), VGPR 64, no spill.  Measured best: 242.4 us.
__global__ __launch_bounds__(256, 4)
void k1_kernel(const float* __restrict__ x, const short* __restrict__ wbf,
               short* __restrict__ att, short* __restrict__ qsg, int n0chunk) {
  __shared__ short SMEM[16384];       // 32768 B: Xs only
  short* Xs = SMEM;

  const int tid  = threadIdx.x;
  const int wave = tid >> 6;          // = head
  const int lane = tid & 63;
  const int g    = lane >> 4;
  const int li   = lane & 15;

  // XCD-aware swizzle: consecutive logical bids (adjacent pixels) on same XCD
  int bid = blockIdx.x;
  const int nb = gridDim.x;
  if ((nb & 7) == 0) { const int q = nb >> 3; bid = (bid & 7) * q + (bid >> 3); }

  const int n0  = n0chunk + bid * 4;
  const int b   = n0 >> 12;
  const int hw0 = n0 & 4095;
  const float* xb = x + (size_t)b * (16 * 256 * 4096) + hw0;

  // ---- Phase 0: stage x tile -> Xs bf16 (4x4 block transpose, HW cvt_pk) ----
  {
    const int c4 = lane;                 // 4-channel block 0..63
    #pragma unroll
    for (int it = 0; it < 4; ++it) {
      const int t = it * 4 + wave;
      const float* src = xb + (size_t)(t * 256 + c4 * 4) * 4096;
      float4 v0 = *(const float4*)(src);
      float4 v1 = *(const float4*)(src + 4096);
      float4 v2 = *(const float4*)(src + 8192);
      float4 v3 = *(const float4*)(src + 12288);
      uint2 s0; s0.x = pk2(v0.x, v1.x); s0.y = pk2(v2.x, v3.x);
      uint2 s1; s1.x = pk2(v0.y, v1.y); s1.y = pk2(v2.y, v3.y);
      uint2 s2; s2.x = pk2(v0.z, v1.z); s2.y = pk2(v2.z, v3.z);
      uint2 s3; s3.x = pk2(v0.w, v1.w); s3.y = pk2(v2.w, v3.w);
      *(uint2*)&Xs[xsw(0 * 16 + t, c4 * 4)] = s0;
      *(uint2*)&Xs[xsw(1 * 16 + t, c4 * 4)] = s1;
      *(uint2*)&Xs[xsw(2 * 16 + t, c4 * 4)] = s2;
      *(uint2*)&Xs[xsw(3 * 16 + t, c4 * 4)] = s3;
    }
  }
  __syncthreads();   // the ONLY barrier

  const short* wq = wbf;
  const short* wk = wbf + 65536;
  const short* wv = wbf + 131072;
  const size_t wrow = (size_t)(wave * 64) * 256;
  // per (px, head) q_soft tile: 16 t x 64 c f16 = 1024 shorts
  short* qsw = qsg + ((size_t)bid * 4 * 4 + wave) * 1024;

  // ---- Pass Q FIRST (all 4 px; scale pre-folded into wq) ----
  {
    f32x4 qacc[4][4];
    #pragma unroll
    for (int p = 0; p < 4; ++p)
      #pragma unroll
      for (int nt = 0; nt < 4; ++nt) qacc[p][nt] = fzero();

    __builtin_amdgcn_s_setprio(1);
    #pragma unroll
    for (int ks = 0; ks < 8; ++ks) {
      bf16x8 qb[4];
      #pragma unroll
      for (int nt = 0; nt < 4; ++nt)
        qb[nt] = *(const bf16x8*)(wq + wrow + (size_t)(nt * 16 + li) * 256 + ks * 32 + g * 8);
      #pragma unroll
      for (int p = 0; p < 4; ++p) {
        bf16x8 af = *(const bf16x8*)&Xs[xsw(p * 16 + li, ks * 32 + g * 8)];
        #pragma unroll
        for (int nt = 0; nt < 4; ++nt)
          qacc[p][nt] = mfma16(af, qb[nt], qacc[p][nt]);
      }
    }
    __builtin_amdgcn_s_setprio(0);

    // Q softmax over c (64 per head), no max-sub -> normalized f16 to qsg
    #pragma unroll
    for (int p = 0; p < 4; ++p) {
      short* qsp = qsw + p * 4096;     // px stride = 4 heads * 1024
      #pragma unroll
      for (int r = 0; r < 4; ++r) {
        float e0 = fexp(qacc[p][0][r]);
        float e1 = fexp(qacc[p][1][r]);
        float e2 = fexp(qacc[p][2][r]);
        float e3 = fexp(qacc[p][3][r]);
        float s = e0 + e1 + e2 + e3;
        s += __shfl_xor(s, 1); s += __shfl_xor(s, 2);
        s += __shfl_xor(s, 4); s += __shfl_xor(s, 8);
        const float inv = frcp(s);
        const int t = g * 4 + r;
        short* dst = qsp + t * 64 + li;
        dst[0]  = f2h(e0 * inv);
        dst[16] = f2h(e1 * inv);
        dst[32] = f2h(e2 * inv);
        dst[48] = f2h(e3 * inv);
      }
    }
  }

  // ---- Pass K (all 4 px) -> t-softmax -> own-lane f16 A-frags ----
  f16x4 akf[4][4];
  {
    f32x4 kacc[4][4];
    #pragma unroll
    for (int p = 0; p < 4; ++p)
      #pragma unroll
      for (int nt = 0; nt < 4; ++nt) kacc[p][nt] = fzero();

    __builtin_amdgcn_s_setprio(1);
    #pragma unroll
    for (int ks = 0; ks < 8; ++ks) {
      bf16x8 kb[4];
      #pragma unroll
      for (int nt = 0; nt < 4; ++nt)
        kb[nt] = *(const bf16x8*)(wk + wrow + (size_t)(nt * 16 + li) * 256 + ks * 32 + g * 8);
      #pragma unroll
      for (int p = 0; p < 4; ++p) {
        bf16x8 af = *(const bf16x8*)&Xs[xsw(p * 16 + li, ks * 32 + g * 8)];
        #pragma unroll
        for (int nt = 0; nt < 4; ++nt)
          kacc[p][nt] = mfma16(af, kb[nt], kacc[p][nt]);
      }
    }
    __builtin_amdgcn_s_setprio(0);

    // softmax over t (4 regs + g-groups), no max-sub (scores ~ N(0,1))
    #pragma unroll
    for (int p = 0; p < 4; ++p)
      #pragma unroll
      for (int nt = 0; nt < 4; ++nt) {
        float e0 = fexp(kacc[p][nt][0]);
        float e1 = fexp(kacc[p][nt][1]);
        float e2 = fexp(kacc[p][nt][2]);
        float e3 = fexp(kacc[p][nt][3]);
        float s = e0 + e1 + e2 + e3;
        s += __shfl_xor(s, 16);
        s += __shfl_xor(s, 32);
        const float inv = frcp(s);
        akf[p][nt] = pkh4(e0 * inv, e1 * inv, e2 * inv, e3 * inv);
      }
  }

  // ---- Pass V (two nt-halves; vacc[4][2] live) -> own-lane f16 B-frags ----
  f16x4 bvf[4][4];
  #pragma unroll
  for (int h = 0; h < 2; ++h) {
    f32x4 vacc[4][2];
    #pragma unroll
    for (int p = 0; p < 4; ++p)
      #pragma unroll
      for (int n2 = 0; n2 < 2; ++n2) vacc[p][n2] = fzero();

    __builtin_amdgcn_s_setprio(1);
    #pragma unroll
    for (int ks = 0; ks < 8; ++ks) {
      bf16x8 vb[2];
      #pragma unroll
      for (int n2 = 0; n2 < 2; ++n2)
        vb[n2] = *(const bf16x8*)(wv + wrow + (size_t)((h * 2 + n2) * 16 + li) * 256 + ks * 32 + g * 8);
      #pragma unroll
      for (int p = 0; p < 4; ++p) {
        bf16x8 af = *(const bf16x8*)&Xs[xsw(p * 16 + li, ks * 32 + g * 8)];
        #pragma unroll
        for (int n2 = 0; n2 < 2; ++n2)
          vacc[p][n2] = mfma16(af, vb[n2], vacc[p][n2]);
      }
    }
    __builtin_amdgcn_s_setprio(0);

    #pragma unroll
    for (int p = 0; p < 4; ++p)
      #pragma unroll
      for (int n2 = 0; n2 < 2; ++n2)
        bvf[p][h * 2 + n2] = pkh4(vacc[p][n2][0], vacc[p][n2][1],
                                  vacc[p][n2][2], vacc[p][n2][3]);
  }

  // ensure this wave's qsg stores are retired before reading them back
  asm volatile("s_waitcnt vmcnt(0)" ::: "memory");

  // ---- Per-pixel stage B: kv (16x16x16 f16) pure-register; out; att store ----
  #pragma unroll
  for (int p = 0; p < 4; ++p) {
    const short* qsp = qsw + p * 4096;
    f32x4 oacc[4];
    #pragma unroll
    for (int nt = 0; nt < 4; ++nt) oacc[nt] = fzero();

    #pragma unroll
    for (int cq = 0; cq < 4; ++cq) {        // c-chunks of 16
      // kv chunk: kva[nt] lane holds kv[c=cq*16+g*4+r][d=nt*16+li]
      f32x4 kva[4];
      #pragma unroll
      for (int nt = 0; nt < 4; ++nt)
        kva[nt] = mfmah(akf[p][cq], bvf[p][nt], fzero());
      // aq: A-frag q_soft[t=li][c=cq*16+g*4+j] from qsg (L2-hot)
      f16x4 aq = ld4h(qsp + li * 64 + cq * 16 + g * 4);
      // kva IS the mfmah B-frag (k=g*4+j, n=li) -> own-lane pack, no transpose
      #pragma unroll
      for (int nt = 0; nt < 4; ++nt) {
        f16x4 kb16 = pkh4(kva[nt][0], kva[nt][1], kva[nt][2], kva[nt][3]);
        oacc[nt] = mfmah(aq, kb16, oacc[nt]);
      }
    }

    const size_t arow = ((size_t)bid * 4 + p) * 16;
    #pragma unroll
    for (int nt = 0; nt < 4; ++nt)
      #pragma unroll
      for (int r = 0; r < 4; ++r)
        att[(arow + g * 4 + r) * 256 + wave * 64 + nt * 16 + li] = f2bf(oacc[nt][r]);
  }
}

// ---------------- K2: out = attn @ Wp^T, transposed coalesced store ----------------
// Round-14 tweak: tile height 128 -> 64 rows (4 t per block, grid x2).
// LDS 67.5 KB -> 33.8 KB = 4 blocks/CU (was 2); acc 128 -> 64 AGPRs.
// Wp L2 re-reads double (L2-resident, cheap) for 2x latency-hiding capacity.
__global__ __launch_bounds__(256, 4)
void k2_kernel(const short* __restrict__ att, const short* __restrict__ wpb,
               float* __restrict__ out, int n0chunk) {
  __shared__ short A[64 * XPAD];
  const int tid = threadIdx.x;
  const int wave = tid >> 6, lane = tid & 63, g = lane >> 4, li = lane & 15;
  const int pb = blockIdx.x >> 2;
  const int t0 = (blockIdx.x & 3) * 4;
  const int n0 = n0chunk + pb * 16;
  const int b = n0 >> 12, hw0 = n0 & 4095;

  for (int idx = tid; idx < 64 * 32; idx += 256) {
    const int row = idx >> 5, seg = idx & 31;
    const int p = row & 15, tl = row >> 4;      // tl 0..3
    const short* src = att + ((size_t)((pb * 16 + p) * 16 + t0 + tl)) * 256 + seg * 8;
    *(int4*)&A[row * XPAD + seg * 8] = *(const int4*)src;
  }
  __syncthreads();

  f32x4 acc[4][4];
  #pragma unroll
  for (int mt = 0; mt < 4; ++mt)
    #pragma unroll
    for (int n4 = 0; n4 < 4; ++n4) acc[mt][n4] = fzero();

  #pragma unroll
  for (int ks = 0; ks < 8; ++ks) {
    bf16x8 bf[4];
    #pragma unroll
    for (int n4 = 0; n4 < 4; ++n4)
      bf[n4] = *(const bf16x8*)(wpb + (size_t)((wave * 4 + n4) * 16 + li) * 256 + ks * 32 + g * 8);
    #pragma unroll
    for (int mt = 0; mt < 4; ++mt) {
      bf16x8 af = *(const bf16x8*)&A[(mt * 16 + li) * XPAD + ks * 32 + g * 8];
      #pragma unroll
      for (int n4 = 0; n4 < 4; ++n4) acc[mt][n4] = mfma16(af, bf[n4], acc[mt][n4]);
    }
  }

  float* ob = out + (size_t)b * (16 * 256 * 4096) + hw0;
  #pragma unroll
  for (int mt = 0; mt < 4; ++mt)
    #pragma unroll
    for (int n4 = 0; n4 < 4; ++n4) {
      const int t = t0 + mt;
      const int c = (wave * 4 + n4) * 16 + li;
      float4 v;
      v.x = acc[mt][n4][0]; v.y = acc[mt][n4][1];
      v.z = acc[mt][n4][2]; v.w = acc[mt][n4][3];
      *(float4*)(ob + (size_t)(t * 256 + c) * 4096 + g * 4) = v;
    }
}

extern "C" void kernel_launch(void* const* d_in, const int* in_sizes, int n_in,
                              void* d_out, int out_size, void* d_ws, size_t ws_size,
                              hipStream_t stream) {
  const float* x  = (const float*)d_in[0];
  const float* Wq = (const float*)d_in[1];
  const float* Wk = (const float*)d_in[2];
  const float* Wv = (const float*)d_in[3];
  const float* Wp = (const float*)d_in[4];
  float* out = (float*)d_out;

  short* wbf = (short*)d_ws;          // 4 x 65536 bf16 = 512 KB
  short* att = wbf + 4 * 65536;       // attn scratch (bf16), chunked

  wconv_kernel<<<256, 256, 0, stream>>>(Wq, Wk, Wv, Wp, wbf);

  const size_t wsAvail = (ws_size > 524288) ? (ws_size - 524288) : 0;
  const size_t perPix = 16 * 256 * 2;  // 8 KB per pixel each for att, qsg
  int chunk = 16;
  while (chunk < 8192 && (size_t)(chunk * 2) * perPix <= wsAvail) chunk <<= 1;

  short* qsg = att + (size_t)chunk * 4096;   // q_soft scratch: chunk x 8 KB

  for (int n0 = 0; n0 < 8192; n0 += chunk) {
    k1_kernel<<<chunk / 4, 256, 0, stream>>>(x, wbf, att, qsg, n0);
    k2_kernel<<<(chunk / 16) * 4, 256, 0, stream>>>(att, wbf + 3 * 65536, out, n0);
  }
}

// Round 15
// 243.442 us; speedup vs baseline: 1.0336x; 1.0336x over previous
//
#include <hip/hip_runtime.h>
#include <hip/hip_bf16.h>

#define DI __device__ __forceinline__

typedef __attribute__((ext_vector_type(8))) short bf16x8;
typedef __attribute__((ext_vector_type(4))) float f32x4;
typedef __attribute__((ext_vector_type(4))) _Float16 f16x4;

constexpr int XPAD = 264;   // k2 A-tile row stride
constexpr float LOG2E = 1.4426950408889634f;

DI float fexp(float x) { return __builtin_amdgcn_exp2f(x * LOG2E); }  // raw v_exp_f32
DI float frcp(float x) { return __builtin_amdgcn_rcpf(x); }           // raw v_rcp_f32

DI short f2bf(float f) {                 // fp32 -> bf16 via HW cvt
  __hip_bfloat16 h = __float2bfloat16(f);
  union { __hip_bfloat16 h; short s; } c; c.h = h; return c.s;
}

DI unsigned pk2(float a, float b) {      // two f32 -> packed bf16x2 (HW cvt_pk)
  union { __hip_bfloat162 h; unsigned u; } c;
  c.h.x = __float2bfloat16(a); c.h.y = __float2bfloat16(b);
  return c.u;
}

DI short f2h(float f) {                  // fp32 -> f16 bits
  _Float16 h = (_Float16)f;
  union { _Float16 h; short s; } c; c.h = h; return c.s;
}

DI f16x4 pkh4(float a, float b, float c, float d) {   // 4 f32 -> f16x4 (cvt_pkrtz)
  auto lo = __builtin_amdgcn_cvt_pkrtz(a, b);         // __fp16 ext_vector(2)
  auto hi = __builtin_amdgcn_cvt_pkrtz(c, d);
  union { struct { decltype(lo) l, h; } p; f16x4 v; } u;
  u.p.l = lo; u.p.h = hi;
  return u.v;
}

DI f16x4 ld4h(const short* p) {          // 4 f16 (8 B)
  union { uint2 u; f16x4 v; } c;
  c.u = *(const uint2*)p;
  return c.v;
}

DI f32x4 mfma16(bf16x8 a, bf16x8 b, f32x4 c) {
  // A: row=l&15, k=(l>>4)*8+j ; B: col=l&15, k=(l>>4)*8+j ; D: col=l&15, row=(l>>4)*4+reg
  return __builtin_amdgcn_mfma_f32_16x16x32_bf16(a, b, c, 0, 0, 0);
}

DI f32x4 mfmah(f16x4 a, f16x4 b, f32x4 c) {
  // 16x16x16 f16: A row=l&15, k=(l>>4)*4+j ; B col=l&15, k=(l>>4)*4+j ; D as above.
  // A/B fragment layout == D layout of the 16x16 family -> GEMM accumulators
  // convert to next-MFMA operands with an own-lane pack (no shfl, no LDS).
  return __builtin_amdgcn_mfma_f32_16x16x16f16(a, b, c, 0, 0, 0);
}

DI f32x4 fzero() { return f32x4{0.f, 0.f, 0.f, 0.f}; }

// Xs swizzled element index: row-major [64][256] bf16, XOR bits 3..5 of the
// element offset with row&7 -> b128 reads across rows hit all 32 banks.
DI int xsw(int row, int e) { return row * 256 + (e ^ ((row & 7) << 3)); }

// ---------------- K0: weights fp32 -> bf16 into ws (Wq pre-scaled) ----------------
__global__ void wconv_kernel(const float* __restrict__ a, const float* __restrict__ b,
                             const float* __restrict__ c, const float* __restrict__ d,
                             short* __restrict__ o) {
  int i = blockIdx.x * 256 + threadIdx.x;
  int mat = i >> 14;                         // block-uniform
  int off = (i & 16383) * 4;
  const float* s = (mat == 0) ? a : (mat == 1) ? b : (mat == 2) ? c : d;
  const float sc = (mat == 0) ? 0.125f : 1.0f;   // fold Ch^-0.5 into Wq
  float4 v = *(const float4*)(s + off);
  uint2 r; r.x = pk2(v.x * sc, v.y * sc); r.y = pk2(v.z * sc, v.w * sc);
  *(uint2*)(o + mat * 65536 + off) = r;
}

// ---------------- K1: fused QKV + softmaxes + linear attention (r11, best) -------
// One WG = 4 consecutive pixels, 256 threads (4 waves). Each wave = one head.
// Direct-x staging (4x4 float4 register transpose -> swizzled Xs), Q-first ->
// qsg (L2-hot), fexp/frcp, register-kv stage B, per-pass accumulators die into
// 16-reg f16 frags, (256,4), VGPR 64, no spill.  Measured best: 242.4 us.
// r15 micro: stage-B aq loads batched per pixel (overlap the 4 L2 latencies).
__global__ __launch_bounds__(256, 4)
void k1_kernel(const float* __restrict__ x, const short* __restrict__ wbf,
               short* __restrict__ att, short* __restrict__ qsg, int n0chunk) {
  __shared__ short SMEM[16384];       // 32768 B: Xs only
  short* Xs = SMEM;

  const int tid  = threadIdx.x;
  const int wave = tid >> 6;          // = head
  const int lane = tid & 63;
  const int g    = lane >> 4;
  const int li   = lane & 15;

  // XCD-aware swizzle: consecutive logical bids (adjacent pixels) on same XCD
  int bid = blockIdx.x;
  const int nb = gridDim.x;
  if ((nb & 7) == 0) { const int q = nb >> 3; bid = (bid & 7) * q + (bid >> 3); }

  const int n0  = n0chunk + bid * 4;
  const int b   = n0 >> 12;
  const int hw0 = n0 & 4095;
  const float* xb = x + (size_t)b * (16 * 256 * 4096) + hw0;

  // ---- Phase 0: stage x tile -> Xs bf16 (4x4 block transpose, HW cvt_pk) ----
  {
    const int c4 = lane;                 // 4-channel block 0..63
    #pragma unroll
    for (int it = 0; it < 4; ++it) {
      const int t = it * 4 + wave;
      const float* src = xb + (size_t)(t * 256 + c4 * 4) * 4096;
      float4 v0 = *(const float4*)(src);
      float4 v1 = *(const float4*)(src + 4096);
      float4 v2 = *(const float4*)(src + 8192);
      float4 v3 = *(const float4*)(src + 12288);
      uint2 s0; s0.x = pk2(v0.x, v1.x); s0.y = pk2(v2.x, v3.x);
      uint2 s1; s1.x = pk2(v0.y, v1.y); s1.y = pk2(v2.y, v3.y);
      uint2 s2; s2.x = pk2(v0.z, v1.z); s2.y = pk2(v2.z, v3.z);
      uint2 s3; s3.x = pk2(v0.w, v1.w); s3.y = pk2(v2.w, v3.w);
      *(uint2*)&Xs[xsw(0 * 16 + t, c4 * 4)] = s0;
      *(uint2*)&Xs[xsw(1 * 16 + t, c4 * 4)] = s1;
      *(uint2*)&Xs[xsw(2 * 16 + t, c4 * 4)] = s2;
      *(uint2*)&Xs[xsw(3 * 16 + t, c4 * 4)] = s3;
    }
  }
  __syncthreads();   // the ONLY barrier

  const short* wq = wbf;
  const short* wk = wbf + 65536;
  const short* wv = wbf + 131072;
  const size_t wrow = (size_t)(wave * 64) * 256;
  // per (px, head) q_soft tile: 16 t x 64 c f16 = 1024 shorts
  short* qsw = qsg + ((size_t)bid * 4 * 4 + wave) * 1024;

  // ---- Pass Q FIRST (all 4 px; scale pre-folded into wq) ----
  {
    f32x4 qacc[4][4];
    #pragma unroll
    for (int p = 0; p < 4; ++p)
      #pragma unroll
      for (int nt = 0; nt < 4; ++nt) qacc[p][nt] = fzero();

    __builtin_amdgcn_s_setprio(1);
    #pragma unroll
    for (int ks = 0; ks < 8; ++ks) {
      bf16x8 qb[4];
      #pragma unroll
      for (int nt = 0; nt < 4; ++nt)
        qb[nt] = *(const bf16x8*)(wq + wrow + (size_t)(nt * 16 + li) * 256 + ks * 32 + g * 8);
      #pragma unroll
      for (int p = 0; p < 4; ++p) {
        bf16x8 af = *(const bf16x8*)&Xs[xsw(p * 16 + li, ks * 32 + g * 8)];
        #pragma unroll
        for (int nt = 0; nt < 4; ++nt)
          qacc[p][nt] = mfma16(af, qb[nt], qacc[p][nt]);
      }
    }
    __builtin_amdgcn_s_setprio(0);

    // Q softmax over c (64 per head), no max-sub -> normalized f16 to qsg
    #pragma unroll
    for (int p = 0; p < 4; ++p) {
      short* qsp = qsw + p * 4096;     // px stride = 4 heads * 1024
      #pragma unroll
      for (int r = 0; r < 4; ++r) {
        float e0 = fexp(qacc[p][0][r]);
        float e1 = fexp(qacc[p][1][r]);
        float e2 = fexp(qacc[p][2][r]);
        float e3 = fexp(qacc[p][3][r]);
        float s = e0 + e1 + e2 + e3;
        s += __shfl_xor(s, 1); s += __shfl_xor(s, 2);
        s += __shfl_xor(s, 4); s += __shfl_xor(s, 8);
        const float inv = frcp(s);
        const int t = g * 4 + r;
        short* dst = qsp + t * 64 + li;
        dst[0]  = f2h(e0 * inv);
        dst[16] = f2h(e1 * inv);
        dst[32] = f2h(e2 * inv);
        dst[48] = f2h(e3 * inv);
      }
    }
  }

  // ---- Pass K (all 4 px) -> t-softmax -> own-lane f16 A-frags ----
  f16x4 akf[4][4];
  {
    f32x4 kacc[4][4];
    #pragma unroll
    for (int p = 0; p < 4; ++p)
      #pragma unroll
      for (int nt = 0; nt < 4; ++nt) kacc[p][nt] = fzero();

    __builtin_amdgcn_s_setprio(1);
    #pragma unroll
    for (int ks = 0; ks < 8; ++ks) {
      bf16x8 kb[4];
      #pragma unroll
      for (int nt = 0; nt < 4; ++nt)
        kb[nt] = *(const bf16x8*)(wk + wrow + (size_t)(nt * 16 + li) * 256 + ks * 32 + g * 8);
      #pragma unroll
      for (int p = 0; p < 4; ++p) {
        bf16x8 af = *(const bf16x8*)&Xs[xsw(p * 16 + li, ks * 32 + g * 8)];
        #pragma unroll
        for (int nt = 0; nt < 4; ++nt)
          kacc[p][nt] = mfma16(af, kb[nt], kacc[p][nt]);
      }
    }
    __builtin_amdgcn_s_setprio(0);

    // softmax over t (4 regs + g-groups), no max-sub (scores ~ N(0,1))
    #pragma unroll
    for (int p = 0; p < 4; ++p)
      #pragma unroll
      for (int nt = 0; nt < 4; ++nt) {
        float e0 = fexp(kacc[p][nt][0]);
        float e1 = fexp(kacc[p][nt][1]);
        float e2 = fexp(kacc[p][nt][2]);
        float e3 = fexp(kacc[p][nt][3]);
        float s = e0 + e1 + e2 + e3;
        s += __shfl_xor(s, 16);
        s += __shfl_xor(s, 32);
        const float inv = frcp(s);
        akf[p][nt] = pkh4(e0 * inv, e1 * inv, e2 * inv, e3 * inv);
      }
  }

  // ---- Pass V (two nt-halves; vacc[4][2] live) -> own-lane f16 B-frags ----
  f16x4 bvf[4][4];
  #pragma unroll
  for (int h = 0; h < 2; ++h) {
    f32x4 vacc[4][2];
    #pragma unroll
    for (int p = 0; p < 4; ++p)
      #pragma unroll
      for (int n2 = 0; n2 < 2; ++n2) vacc[p][n2] = fzero();

    __builtin_amdgcn_s_setprio(1);
    #pragma unroll
    for (int ks = 0; ks < 8; ++ks) {
      bf16x8 vb[2];
      #pragma unroll
      for (int n2 = 0; n2 < 2; ++n2)
        vb[n2] = *(const bf16x8*)(wv + wrow + (size_t)((h * 2 + n2) * 16 + li) * 256 + ks * 32 + g * 8);
      #pragma unroll
      for (int p = 0; p < 4; ++p) {
        bf16x8 af = *(const bf16x8*)&Xs[xsw(p * 16 + li, ks * 32 + g * 8)];
        #pragma unroll
        for (int n2 = 0; n2 < 2; ++n2)
          vacc[p][n2] = mfma16(af, vb[n2], vacc[p][n2]);
      }
    }
    __builtin_amdgcn_s_setprio(0);

    #pragma unroll
    for (int p = 0; p < 4; ++p)
      #pragma unroll
      for (int n2 = 0; n2 < 2; ++n2)
        bvf[p][h * 2 + n2] = pkh4(vacc[p][n2][0], vacc[p][n2][1],
                                  vacc[p][n2][2], vacc[p][n2][3]);
  }

  // ensure this wave's qsg stores are retired before reading them back
  asm volatile("s_waitcnt vmcnt(0)" ::: "memory");

  // ---- Per-pixel stage B: kv (16x16x16 f16) pure-register; out; att store ----
  #pragma unroll
  for (int p = 0; p < 4; ++p) {
    const short* qsp = qsw + p * 4096;

    // batch the 4 A-frag loads for this px: their L2 latencies overlap
    // instead of serializing one per cq iteration (+8 regs, static index)
    f16x4 aq[4];
    #pragma unroll
    for (int cq = 0; cq < 4; ++cq)
      aq[cq] = ld4h(qsp + li * 64 + cq * 16 + g * 4);

    f32x4 oacc[4];
    #pragma unroll
    for (int nt = 0; nt < 4; ++nt) oacc[nt] = fzero();

    #pragma unroll
    for (int cq = 0; cq < 4; ++cq) {        // c-chunks of 16
      // kv chunk: kva[nt] lane holds kv[c=cq*16+g*4+r][d=nt*16+li]
      f32x4 kva[4];
      #pragma unroll
      for (int nt = 0; nt < 4; ++nt)
        kva[nt] = mfmah(akf[p][cq], bvf[p][nt], fzero());
      // kva IS the mfmah B-frag (k=g*4+j, n=li) -> own-lane pack, no transpose
      #pragma unroll
      for (int nt = 0; nt < 4; ++nt) {
        f16x4 kb16 = pkh4(kva[nt][0], kva[nt][1], kva[nt][2], kva[nt][3]);
        oacc[nt] = mfmah(aq[cq], kb16, oacc[nt]);
      }
    }

    const size_t arow = ((size_t)bid * 4 + p) * 16;
    #pragma unroll
    for (int nt = 0; nt < 4; ++nt)
      #pragma unroll
      for (int r = 0; r < 4; ++r)
        att[(arow + g * 4 + r) * 256 + wave * 64 + nt * 16 + li] = f2bf(oacc[nt][r]);
  }
}

// ---------------- K2: out = attn @ Wp^T, transposed coalesced store ----------------
// (r11's proven 128-row tile; r14's 64-row halving regressed -9 us --
//  weight-read latency per block is constant, so halving work per block
//  loses amortization: same law as r3/r9.)
__global__ __launch_bounds__(256, 2)
void k2_kernel(const short* __restrict__ att, const short* __restrict__ wpb,
               float* __restrict__ out, int n0chunk) {
  __shared__ short A[128 * XPAD];
  const int tid = threadIdx.x;
  const int wave = tid >> 6, lane = tid & 63, g = lane >> 4, li = lane & 15;
  const int pb = blockIdx.x >> 1;
  const int t0 = (blockIdx.x & 1) * 8;
  const int n0 = n0chunk + pb * 16;
  const int b = n0 >> 12, hw0 = n0 & 4095;

  for (int idx = tid; idx < 128 * 32; idx += 256) {
    const int row = idx >> 5, seg = idx & 31;
    const int p = row & 15, tl = row >> 4;
    const short* src = att + ((size_t)((pb * 16 + p) * 16 + t0 + tl)) * 256 + seg * 8;
    *(int4*)&A[row * XPAD + seg * 8] = *(const int4*)src;
  }
  __syncthreads();

  f32x4 acc[8][4];
  #pragma unroll
  for (int mt = 0; mt < 8; ++mt)
    #pragma unroll
    for (int n4 = 0; n4 < 4; ++n4) acc[mt][n4] = fzero();

  #pragma unroll
  for (int ks = 0; ks < 8; ++ks) {
    bf16x8 bf[4];
    #pragma unroll
    for (int n4 = 0; n4 < 4; ++n4)
      bf[n4] = *(const bf16x8*)(wpb + (size_t)((wave * 4 + n4) * 16 + li) * 256 + ks * 32 + g * 8);
    #pragma unroll
    for (int mt = 0; mt < 8; ++mt) {
      bf16x8 af = *(const bf16x8*)&A[(mt * 16 + li) * XPAD + ks * 32 + g * 8];
      #pragma unroll
      for (int n4 = 0; n4 < 4; ++n4) acc[mt][n4] = mfma16(af, bf[n4], acc[mt][n4]);
    }
  }

  float* ob = out + (size_t)b * (16 * 256 * 4096) + hw0;
  #pragma unroll
  for (int mt = 0; mt < 8; ++mt)
    #pragma unroll
    for (int n4 = 0; n4 < 4; ++n4) {
      const int t = t0 + mt;
      const int c = (wave * 4 + n4) * 16 + li;
      float4 v;
      v.x = acc[mt][n4][0]; v.y = acc[mt][n4][1];
      v.z = acc[mt][n4][2]; v.w = acc[mt][n4][3];
      *(float4*)(ob + (size_t)(t * 256 + c) * 4096 + g * 4) = v;
    }
}

extern "C" void kernel_launch(void* const* d_in, const int* in_sizes, int n_in,
                              void* d_out, int out_size, void* d_ws, size_t ws_size,
                              hipStream_t stream) {
  const float* x  = (const float*)d_in[0];
  const float* Wq = (const float*)d_in[1];
  const float* Wk = (const float*)d_in[2];
  const float* Wv = (const float*)d_in[3];
  const float* Wp = (const float*)d_in[4];
  float* out = (float*)d_out;

  short* wbf = (short*)d_ws;          // 4 x 65536 bf16 = 512 KB
  short* att = wbf + 4 * 65536;       // attn scratch (bf16), chunked

  wconv_kernel<<<256, 256, 0, stream>>>(Wq, Wk, Wv, Wp, wbf);

  const size_t wsAvail = (ws_size > 524288) ? (ws_size - 524288) : 0;
  const size_t perPix = 16 * 256 * 2;  // 8 KB per pixel each for att, qsg
  int chunk = 16;
  while (chunk < 8192 && (size_t)(chunk * 2) * perPix <= wsAvail) chunk <<= 1;

  short* qsg = att + (size_t)chunk * 4096;   // q_soft scratch: chunk x 8 KB

  for (int n0 = 0; n0 < 8192; n0 += chunk) {
    k1_kernel<<<chunk / 4, 256, 0, stream>>>(x, wbf, att, qsg, n0);
    k2_kernel<<<(chunk / 16) * 2, 256, 0, stream>>>(att, wbf + 3 * 65536, out, n0);
  }
}